// Round 2
// 332.294 us; speedup vs baseline: 1.0716x; 1.0716x over previous
//
#include <hip/hip_runtime.h>

// ---------- constants for this problem ----------
// B=4, N=2048, C=1024, H=16, D=64; M = B*N = 8192
#define MM   8192
#define CC   1024
#define F3   3072
#define NN   2048
#define HH   16
#define DD   64
// q scale: D^-0.5 * log2(e), folded into q during RoPE so softmax uses exp2
#define QSCALE 0.1803368801111731f

typedef __attribute__((ext_vector_type(8))) __bf16 bf16x8;
typedef __attribute__((ext_vector_type(4))) float floatx4;
typedef __attribute__((ext_vector_type(4))) unsigned uintx4;

__device__ __forceinline__ unsigned short f2b(float f) {
  union { float f; unsigned int u; } v; v.f = f;
  unsigned int r = v.u + 0x7fffu + ((v.u >> 16) & 1u);
  return (unsigned short)(r >> 16);
}
__device__ __forceinline__ float b2f(unsigned short b) {
  union { unsigned int u; float f; } v; v.u = ((unsigned int)b) << 16;
  return v.f;
}

// async global->LDS, 16B per lane. LDS dest is wave-uniform base + lane*16,
// so the LDS layout must be lane-linear (no padding) in chunk order.
__device__ __forceinline__ void gl_lds16(const unsigned short* g, unsigned short* l) {
  __builtin_amdgcn_global_load_lds((const __attribute__((address_space(1))) void*)g,
                                   (__attribute__((address_space(3))) void*)l, 16, 0, 0);
}

// ---------- fp32 -> bf16 conversion (vectorized x4) ----------
__global__ __launch_bounds__(256) void f32_to_bf16_k(const float* __restrict__ in,
                                                     unsigned short* __restrict__ out, int n4) {
  int i = blockIdx.x * 256 + threadIdx.x;
  if (i < n4) {
    float4 v = ((const float4*)in)[i];
    ushort4 o;
    o.x = f2b(v.x); o.y = f2b(v.y); o.z = f2b(v.z); o.w = f2b(v.w);
    ((ushort4*)out)[i] = o;
  }
}

// ---------- GEMM: A[M,K] bf16 row-major  x  Bm[F,K] bf16 row-major (B^T layout) ----------
// 128x128 tile, 4 waves (2x2 of 64x64), 16x16x32 bf16 MFMA, BK=32.
// ROPE=true (GEMM1): each wave's 64-col slice is one head; the RoPE pair
// (d, d+32) is acc[im][jf] / acc[im][jf+2] in the SAME lane -> rotate in
// registers on fp32 accumulators, wave-uniform branch on head<32, q scaled.
template <int F, bool BF16OUT, bool ROPE>
__global__ __launch_bounds__(256) void gemm_bt(const unsigned short* __restrict__ A,
                                               const unsigned short* __restrict__ Bm,
                                               void* __restrict__ Cout,
                                               const float* __restrict__ bias,
                                               const float* __restrict__ rcp,
                                               const float* __restrict__ spp, int K) {
  __shared__ alignas(16) unsigned short lA[128 * 32];
  __shared__ alignas(16) unsigned short lB[128 * 32];
  const int tid = threadIdx.x, lane = tid & 63, wave = tid >> 6;
  const int r16 = lane & 15, q4 = lane >> 4;
  const int rowBase = blockIdx.x * 128, colBase = blockIdx.y * 128;
  const int wm = wave & 1, wf = wave >> 1;

  floatx4 acc[4][4];
  const floatx4 z = {0.f, 0.f, 0.f, 0.f};
  for (int i = 0; i < 4; ++i)
    for (int j = 0; j < 4; ++j) acc[i][j] = z;

  for (int k0 = 0; k0 < K; k0 += 32) {
    __syncthreads();
#pragma unroll
    for (int i = 0; i < 2; ++i) {
      int chunk = i * 256 + tid;            // 0..511, 16B each; LDS off = chunk*16B
      int row = chunk >> 2, col = (chunk & 3) * 8;
      gl_lds16(A + (size_t)(rowBase + row) * K + k0 + col, &lA[chunk * 8]);
      gl_lds16(Bm + (size_t)(colBase + row) * K + k0 + col, &lB[chunk * 8]);
    }
    __syncthreads();
    bf16x8 af[4];
    for (int im = 0; im < 4; ++im)
      af[im] = *(const bf16x8*)(&lA[(wm * 64 + im * 16 + r16) * 32 + q4 * 8]);
    for (int jf = 0; jf < 4; ++jf) {
      bf16x8 bfr = *(const bf16x8*)(&lB[(wf * 64 + jf * 16 + r16) * 32 + q4 * 8]);
      for (int im = 0; im < 4; ++im)
        acc[im][jf] = __builtin_amdgcn_mfma_f32_16x16x32_bf16(af[im], bfr, acc[im][jf], 0, 0, 0);
    }
  }

  if (ROPE) {
    int head = (colBase >> 6) + wf;          // 0..47; q:0-15, k:16-31, v:32-47
    if (head < 32) {
      const bool isq = head < 16;
      for (int im = 0; im < 4; ++im)
        for (int jf = 0; jf < 2; ++jf)
          for (int r = 0; r < 4; ++r) {
            int grow = rowBase + wm * 64 + im * 16 + q4 * 4 + r;
            int n = grow & (NN - 1);
            int dp = jf * 16 + r16;          // 0..31
            float x0 = acc[im][jf][r], x1 = acc[im][jf + 2][r];
            float c0 = rcp[n * DD + dp],      s0v = spp[n * DD + dp];
            float c1 = rcp[n * DD + dp + 32], s1v = spp[n * DD + dp + 32];
            float y0 = x0 * c0 - x1 * s0v;
            float y1 = x1 * c1 + x0 * s1v;
            if (isq) { y0 *= QSCALE; y1 *= QSCALE; }
            acc[im][jf][r] = y0;
            acc[im][jf + 2][r] = y1;
          }
    }
  }

  for (int im = 0; im < 4; ++im)
    for (int jf = 0; jf < 4; ++jf)
      for (int r = 0; r < 4; ++r) {
        int grow = rowBase + wm * 64 + im * 16 + q4 * 4 + r;
        int gcol = colBase + wf * 64 + jf * 16 + r16;
        if (BF16OUT)
          ((unsigned short*)Cout)[(size_t)grow * F + gcol] = f2b(acc[im][jf][r]);
        else
          ((float*)Cout)[(size_t)grow * F + gcol] = acc[im][jf][r] + bias[gcol];
      }
}

// ---------- flash attention v6b ----------
// grid: (N/128, B*H). block: 256 (4 waves, 32 q-rows each). KV tile 64.
// R6 (T12 in-register softmax), R7 fix:
//  * QK^T operands SWAPPED: s = mfma(kf, qf) -> S^T layout, lane (r16=q, q4=g)
//    holds P[q][k=jn*16+g*4+r] — softmax row spread over the 4 g-groups.
//  * P -> bf16 via v_cvt_pk_bf16_f32 (RNE, S0->low half; m214v22-validated),
//    then redistributed to the PV A-fragment with v_permlane32_swap (swap
//    x-hi-half <-> y-lo-half; m214v22-validated) followed by an UNAMBIGUOUS
//    16-row exchange: shfl_xor(·,16) + row-parity select.
//    R7 post-mortem: R6 used v_permlane16_swap_b32 for the second exchange
//    and failed at 0.9% absmax — exactly the within-row k-permutation
//    signature. Its row-pairing on gfx950 differs from my assumption; do
//    NOT reintroduce it without an isolated lane-identity probe.
//  * l accumulated from f32 P (RNE is unbiased); reduced xor16/xor32 +
//    shfl broadcast in the epilogue.
//  * sPQ eliminated; Q fragments read direct from global once per block.
//    LDS 34.8 KB -> 16.4 KB.
// NOTE (R5 post-mortem): register-funded cross-iteration pipelining beyond
// the existing 1-deep K/V reg prefetch regressed occupancy — do not re-add.
__global__ __launch_bounds__(256, 4) void attn_k(const unsigned short* __restrict__ qkv,
                                                 unsigned short* __restrict__ obuf) {
  __shared__ alignas(16) unsigned short sK[64 * 64];
  __shared__ alignas(16) unsigned short sVT[64 * 64];

  const int tid = threadIdx.x, lane = tid & 63, wave = tid >> 6;
  const int r16 = lane & 15, q4 = lane >> 4;
  const int q0 = blockIdx.x * 128;
  const int bh = blockIdx.y, b = bh >> 4, h = bh & 15;
  const unsigned short* qbase = qkv + (size_t)(b * NN) * F3 + h * DD;

  // Q fragments direct from global (once per block). B-operand layout:
  // lane (r16,q4) holds Q[q=...+r16][d=kk*32+q4*8 .. +7] — plain 16B read.
  bf16x8 qf[2][2];
#pragma unroll
  for (int im = 0; im < 2; ++im)
#pragma unroll
    for (int kk = 0; kk < 2; ++kk)
      qf[im][kk] = *(const bf16x8*)(qbase +
          (size_t)(q0 + wave * 32 + im * 16 + r16) * F3 + kk * 32 + q4 * 8);

  const floatx4 z = {0.f, 0.f, 0.f, 0.f};
  floatx4 o[2][4];
  float lacc[2] = {0.f, 0.f};
#pragma unroll
  for (int im = 0; im < 2; ++im)
    for (int jd = 0; jd < 4; ++jd) o[im][jd] = z;

  const int krow0 = tid >> 3, kc8 = tid & 7;
  const int vkvp = tid >> 3, vc8 = tid & 7;

  // prefetch t=0 K/V into regs
  const unsigned short* kvb = qbase;
  int4 kreg0 = *(const int4*)(kvb + (size_t)krow0 * F3 + CC + kc8 * 8);
  int4 kreg1 = *(const int4*)(kvb + (size_t)(krow0 + 32) * F3 + CC + kc8 * 8);
  int4 vreg0 = *(const int4*)(kvb + (size_t)(2 * vkvp) * F3 + 2 * CC + vc8 * 8);
  int4 vreg1 = *(const int4*)(kvb + (size_t)(2 * vkvp + 1) * F3 + 2 * CC + vc8 * 8);

  for (int t = 0; t < NN / 64; ++t) {
    __syncthreads();   // previous iter's LDS reads complete

    // stage K_t (swizzled b128) and V_t (transposed, perm-packed b32)
    *(int4*)(&sK[krow0 * 64 + ((kc8 ^ (krow0 & 7)) << 3)]) = kreg0;
    *(int4*)(&sK[(krow0 + 32) * 64 + ((kc8 ^ ((krow0 + 32) & 7)) << 3)]) = kreg1;
    {
      const unsigned* a0 = (const unsigned*)&vreg0;
      const unsigned* a1 = (const unsigned*)&vreg1;
#pragma unroll
      for (int w = 0; w < 4; ++w) {
        unsigned lo = __builtin_amdgcn_perm(a1[w], a0[w], 0x05040100u);
        unsigned hi = __builtin_amdgcn_perm(a1[w], a0[w], 0x07060302u);
        int d0 = vc8 * 8 + 2 * w;
        int sw0 = (2 * w + vc8) & 7;
        int sw1 = (2 * w + 1 + vc8) & 7;
        *(unsigned*)(&sVT[d0 * 64 + (((vkvp >> 2) ^ sw0) << 3) + 2 * (vkvp & 3)]) = lo;
        *(unsigned*)(&sVT[(d0 + 1) * 64 + (((vkvp >> 2) ^ sw1) << 3) + 2 * (vkvp & 3)]) = hi;
      }
    }

    // prefetch t+1 (overlaps compute below)
    if (t + 1 < NN / 64) {
      const unsigned short* nb = qkv + (size_t)(b * NN + (t + 1) * 64) * F3 + h * DD;
      kreg0 = *(const int4*)(nb + (size_t)krow0 * F3 + CC + kc8 * 8);
      kreg1 = *(const int4*)(nb + (size_t)(krow0 + 32) * F3 + CC + kc8 * 8);
      vreg0 = *(const int4*)(nb + (size_t)(2 * vkvp) * F3 + 2 * CC + vc8 * 8);
      vreg1 = *(const int4*)(nb + (size_t)(2 * vkvp + 1) * F3 + 2 * CC + vc8 * 8);
    }

    __syncthreads();   // K_t/V_t visible

    // S^T = K Q^T : lane (r16=q, g=q4) gets P[q][k=jn*16+g*4+r]
    floatx4 s[2][4];
#pragma unroll
    for (int jn = 0; jn < 4; ++jn) {
      int row = jn * 16 + r16;
      bf16x8 kf0 = *(const bf16x8*)(&sK[row * 64 + ((q4 ^ (row & 7)) << 3)]);
      bf16x8 kf1 = *(const bf16x8*)(&sK[row * 64 + (((4 + q4) ^ (row & 7)) << 3)]);
#pragma unroll
      for (int im = 0; im < 2; ++im) {
        floatx4 a = z;
        a = __builtin_amdgcn_mfma_f32_16x16x32_bf16(kf0, qf[im][0], a, 0, 0, 0);
        a = __builtin_amdgcn_mfma_f32_16x16x32_bf16(kf1, qf[im][1], a, 0, 0, 0);
        s[im][jn] = a;
      }
    }

    // P = exp2(S^T); pack to bf16 (RNE) and redistribute in-register.
    // B(j2,g) := pack(P[q][kk*32 + j2*16 + g*4 + 2t], ..+1) held at group g.
    // Need at group g': word t2   = B(g'>>1, 2(g'&1))
    //                   word 2+t2 = B(g'>>1, 2(g'&1)+1)
    // permlane32_swap (x-hi <-> y-lo):
    //   x = {B(0,0),B(0,1),B(1,0),B(1,1)}, y = {B(0,2),B(0,3),B(1,2),B(1,3)}
    // then 16-row exchange via shfl_xor(16) + odd-row select:
    //   x' = odd ? xor16(y) : x  -> {B(0,0),B(0,2),B(1,0),B(1,2)}  (words 0,1)
    //   y' = odd ? y : xor16(x)  -> {B(0,1),B(0,3),B(1,1),B(1,3)}  (words 2,3)
    bf16x8 pf[2][2];
    const bool oddrow = (q4 & 1) != 0;
#pragma unroll
    for (int im = 0; im < 2; ++im) {
#pragma unroll
      for (int kk = 0; kk < 2; ++kk) {
        unsigned bw[2][2];   // [j2 = jn-2kk][t]
#pragma unroll
        for (int j2 = 0; j2 < 2; ++j2) {
          int jn = 2 * kk + j2;
          float p0 = __builtin_amdgcn_exp2f(s[im][jn][0]);
          float p1 = __builtin_amdgcn_exp2f(s[im][jn][1]);
          float p2 = __builtin_amdgcn_exp2f(s[im][jn][2]);
          float p3 = __builtin_amdgcn_exp2f(s[im][jn][3]);
          lacc[im] += (p0 + p1) + (p2 + p3);
          asm("v_cvt_pk_bf16_f32 %0, %1, %2" : "=v"(bw[j2][0]) : "v"(p0), "v"(p1));
          asm("v_cvt_pk_bf16_f32 %0, %1, %2" : "=v"(bw[j2][1]) : "v"(p2), "v"(p3));
        }
        uintx4 pk;
#pragma unroll
        for (int t2 = 0; t2 < 2; ++t2) {
          unsigned x = bw[0][t2], y = bw[1][t2];
          asm("v_permlane32_swap_b32 %0, %1" : "+v"(x), "+v"(y));
          unsigned xa = (unsigned)__shfl_xor((int)y, 16);
          unsigned ya = (unsigned)__shfl_xor((int)x, 16);
          pk[t2]     = oddrow ? xa : x;
          pk[2 + t2] = oddrow ? y  : ya;
        }
        pf[im][kk] = __builtin_bit_cast(bf16x8, pk);
      }
    }

    // O += P V
#pragma unroll
    for (int jd = 0; jd < 4; ++jd) {
      int d = jd * 16 + r16;
      int swr = (d + (d >> 3)) & 7;
      bf16x8 vf0 = *(const bf16x8*)(&sVT[d * 64 + ((q4 ^ swr) << 3)]);
      bf16x8 vf1 = *(const bf16x8*)(&sVT[d * 64 + (((4 + q4) ^ swr) << 3)]);
#pragma unroll
      for (int im = 0; im < 2; ++im) {
        o[im][jd] = __builtin_amdgcn_mfma_f32_16x16x32_bf16(pf[im][0], vf0, o[im][jd], 0, 0, 0);
        o[im][jd] = __builtin_amdgcn_mfma_f32_16x16x32_bf16(pf[im][1], vf1, o[im][jd], 0, 0, 0);
      }
    }
  }

  // epilogue: l partial over g groups at lanes sharing r16 -> reduce across
  // g (xor 16/32), then shfl-broadcast inv to the o row mapping
  // (o row = q4*4+r; inv for that row lives at lane r16 == q4*4+r).
#pragma unroll
  for (int im = 0; im < 2; ++im) {
    float l = lacc[im];
    l += __shfl_xor(l, 16);
    l += __shfl_xor(l, 32);
    float inv = 1.0f / l;
#pragma unroll
    for (int r = 0; r < 4; ++r) {
      float invr = __shfl(inv, q4 * 4 + r);
      int row = q0 + wave * 32 + im * 16 + q4 * 4 + r;
#pragma unroll
      for (int jd = 0; jd < 4; ++jd) {
        int col = h * DD + jd * 16 + r16;
        obuf[(size_t)(b * NN + row) * CC + col] = f2b(o[im][jd][r] * invr);
      }
    }
  }
}

// ---------- launcher ----------
extern "C" void kernel_launch(void* const* d_in, const int* in_sizes, int n_in,
                              void* d_out, int out_size, void* d_ws, size_t ws_size,
                              hipStream_t stream) {
  const float* x     = (const float*)d_in[0];
  const float* rc    = (const float*)d_in[1];
  const float* rs    = (const float*)d_in[2];
  const float* wqkv  = (const float*)d_in[3];
  const float* wproj = (const float*)d_in[4];
  const float* bproj = (const float*)d_in[5];
  float* out = (float*)d_out;

  char* w = (char*)d_ws;
  unsigned short* xb     = (unsigned short*)(w);                       // 16,777,216 B
  unsigned short* wqkvb  = (unsigned short*)(w + 16777216);            //  6,291,456 B
  unsigned short* wprojb = (unsigned short*)(w + 23068672);            //  2,097,152 B
  unsigned short* qkvb   = (unsigned short*)(w + 25165824);            // 50,331,648 B
  unsigned short* obuf   = (unsigned short*)(w + 75497472);            // 16,777,216 B

  f32_to_bf16_k<<<(MM * CC / 4 + 255) / 256, 256, 0, stream>>>(x, xb, MM * CC / 4);
  f32_to_bf16_k<<<(F3 * CC / 4 + 255) / 256, 256, 0, stream>>>(wqkv, wqkvb, F3 * CC / 4);
  f32_to_bf16_k<<<(CC * CC / 4 + 255) / 256, 256, 0, stream>>>(wproj, wprojb, CC * CC / 4);

  // GEMM1 with fused RoPE epilogue (rope_k dispatch eliminated)
  gemm_bt<F3, true, true><<<dim3(MM / 128, F3 / 128), 256, 0, stream>>>(
      xb, wqkvb, qkvb, nullptr, rc, rs, CC);

  attn_k<<<dim3(NN / 128, 4 * HH), 256, 0, stream>>>(qkvb, obuf);

  gemm_bt<CC, false, false><<<dim3(MM / 128, CC / 128), 256, 0, stream>>>(
      obuf, wprojb, out, bproj, nullptr, nullptr, CC);
}